// Round 3
// baseline (5283.687 us; speedup 1.0000x reference)
//
#include <hip/hip_runtime.h>
#include <math.h>

#define C_DIM 1280
#define T_DIM 1024
#define NIMG 5
#define HEADS 20
#define HD 64
#define NSEL 512
#define MROWS (10 * T_DIM)      // 10240
#define SCTX (4 * NSEL + T_DIM) // 3072
#define QT 256
#define KT 64
#define NT (SCTX / KT)          // 48

// ---------------------------------------------------------------------------
// Kernel 1: fused QKV projection GEMM (unchanged; ~80% of f32 vector peak).
// X (10240 x 1280) @ {Wq|Wk|Wv} -> Q/K/V in [n][h][t][d] layout.
// ---------------------------------------------------------------------------
__global__ __launch_bounds__(256) void qkv_gemm(
    const float* __restrict__ X, const float* __restrict__ Wq,
    const float* __restrict__ Wk, const float* __restrict__ Wv,
    float* __restrict__ Qo, float* __restrict__ Ko, float* __restrict__ Vo)
{
    __shared__ float As[16][132];
    __shared__ float Bs[16][132];
    const int tid = threadIdx.x;
    const int tx = tid & 15, ty = tid >> 4;
    const int bn = blockIdx.x;
    const int bm = blockIdx.y;
    const int wsel = bn / 10;
    const int cW = (bn - wsel * 10) * 128;
    const float* __restrict__ W = (wsel == 0) ? Wq : (wsel == 1) ? Wk : Wv;
    float* __restrict__ Out = (wsel == 0) ? Qo : (wsel == 1) ? Ko : Vo;
    const int r0 = bm * 128;

    float acc[2][2][4][4];
    #pragma unroll
    for (int a = 0; a < 2; a++)
        #pragma unroll
        for (int b = 0; b < 2; b++)
            #pragma unroll
            for (int i = 0; i < 4; i++)
                #pragma unroll
                for (int j = 0; j < 4; j++) acc[a][b][i][j] = 0.f;

    for (int kk = 0; kk < C_DIM; kk += 16) {
        #pragma unroll
        for (int rep = 0; rep < 2; rep++) {
            int flat = rep * 256 + tid;
            int row = flat >> 2, ch = flat & 3;
            float4 v = *(const float4*)(X + (size_t)(r0 + row) * C_DIM + kk + ch * 4);
            As[ch * 4 + 0][row] = v.x;
            As[ch * 4 + 1][row] = v.y;
            As[ch * 4 + 2][row] = v.z;
            As[ch * 4 + 3][row] = v.w;
        }
        #pragma unroll
        for (int rep = 0; rep < 2; rep++) {
            int flat = rep * 256 + tid;
            int row = flat >> 5, ch = flat & 31;
            *(float4*)&Bs[row][ch * 4] =
                *(const float4*)(W + (size_t)(kk + row) * C_DIM + cW + ch * 4);
        }
        __syncthreads();
        #pragma unroll
        for (int k = 0; k < 16; k++) {
            float4 a0 = *(float4*)&As[k][ty * 4];
            float4 a1 = *(float4*)&As[k][64 + ty * 4];
            float4 b0 = *(float4*)&Bs[k][tx * 4];
            float4 b1 = *(float4*)&Bs[k][64 + tx * 4];
            float av[2][4] = {{a0.x, a0.y, a0.z, a0.w}, {a1.x, a1.y, a1.z, a1.w}};
            float bv[2][4] = {{b0.x, b0.y, b0.z, b0.w}, {b1.x, b1.y, b1.z, b1.w}};
            #pragma unroll
            for (int p = 0; p < 2; p++)
                #pragma unroll
                for (int q = 0; q < 4; q++)
                    #pragma unroll
                    for (int u = 0; u < 2; u++)
                        #pragma unroll
                        for (int w = 0; w < 4; w++)
                            acc[p][u][q][w] += av[p][q] * bv[u][w];
        }
        __syncthreads();
    }
    #pragma unroll
    for (int rb = 0; rb < 2; rb++)
        #pragma unroll
        for (int rr = 0; rr < 4; rr++) {
            int r = r0 + rb * 64 + ty * 4 + rr;
            int n = r >> 10, t = r & 1023;
            #pragma unroll
            for (int cb = 0; cb < 2; cb++) {
                int c = cW + cb * 64 + tx * 4;
                int h = c >> 6, d = c & 63;
                float4 v = make_float4(acc[rb][cb][rr][0], acc[rb][cb][rr][1],
                                       acc[rb][cb][rr][2], acc[rb][cb][rr][3]);
                *(float4*)(Out + ((size_t)((n * HEADS + h) * T_DIM + t)) * HD + d) = v;
            }
        }
}

// ---------------------------------------------------------------------------
// Kernel 2: flash attention v2 — 8x8 micro-tiles, Q-tile 256, K-tile 64.
// 256 threads: tid = rg*8+kg; rg=0..31 owns q-rows rg*8..+7; kg=0..7 owns
// 8 k-cols (QK) / 8 d-cols (PV). Softmax reduces over kg via shfl_xor(1,2,4).
// LDS 160KB exact: Qs[64][256] + Ks[64][64] + Vs[64][64] + Ps[64][256].
// Swizzle: col ^= 4*((row>>3)&7) keeps all patterns <=2-way even (free).
// K/V(t+1) prefetched to regs at loop top, written to LDS between barriers.
// ---------------------------------------------------------------------------
__global__ __launch_bounds__(256, 1) void flash_attn(
    const float* __restrict__ Qg, const float* __restrict__ Kg,
    const float* __restrict__ Vg, const int* __restrict__ idxg,
    float* __restrict__ Og)
{
    __shared__ __align__(16) float lds[40960];   // 163840 B = 160 KiB
    float* __restrict__ Qs = lds;                // [64][256] swizzled
    float* __restrict__ Ks = lds + 16384;        // [64][64]  swizzled
    float* __restrict__ Vs = lds + 20480;        // [64][64]  natural
    float* __restrict__ Ps = lds + 24576;        // [64][256] swizzled

    const int tid = threadIdx.x;
    const int kg = tid & 7;      // col-group (QK) / d-group (PV)
    const int rg = tid >> 3;     // row-group 0..31
    const int qt = blockIdx.x, h = blockIdx.y, n = blockIdx.z;
    const int b = n / NIMG, i = n - b * NIMG;
    int jl[4];
    { int c = 0; for (int j = 0; j < NIMG; j++) if (j != i) jl[c++] = j; }

    const int glr = tid >> 4;          // gather: local row within 16-group
    const int gld = (tid & 15) * 4;    // gather: d offset (float4)

    // ---- Q stage: 256 rows, transposed + swizzled + pre-scaled ----
    {
        const size_t qbase = ((size_t)(n * HEADS + h)) * T_DIM * HD + (size_t)qt * QT * HD;
        #pragma unroll
        for (int rep = 0; rep < 16; rep++) {
            int r = rep * 16 + glr;
            float4 v = *(const float4*)(Qg + qbase + (size_t)r * HD + gld);
            float vv[4] = {v.x, v.y, v.z, v.w};
            #pragma unroll
            for (int e = 0; e < 4; e++) {
                int d = gld + e;
                int sd = 4 * ((d >> 3) & 7);
                Qs[d * 256 + (r ^ sd)] = vv[e] * 0.125f;
            }
        }
    }

    float4 kreg[4], vreg[4];
    int klocal[4];
    #pragma unroll
    for (int rep = 0; rep < 4; rep++) klocal[rep] = rep * 16 + glr;

    // gather K/V rows of ctx tile t into registers
    auto gather = [&](int t) {
        #pragma unroll
        for (int rep = 0; rep < 4; rep++) {
            int cr = t * KT + klocal[rep];
            int j, st;
            if (cr < 4 * NSEL) { j = jl[cr >> 9]; st = idxg[j * NSEL + (cr & (NSEL - 1))]; }
            else               { j = i;           st = cr - 4 * NSEL; }
            size_t base = (((size_t)(b * NIMG + j) * HEADS + h) * T_DIM + st) * HD;
            kreg[rep] = *(const float4*)(Kg + base + gld);
            vreg[rep] = *(const float4*)(Vg + base + gld);
        }
    };
    auto writeK = [&]() {
        #pragma unroll
        for (int rep = 0; rep < 4; rep++) {
            float kv[4] = {kreg[rep].x, kreg[rep].y, kreg[rep].z, kreg[rep].w};
            #pragma unroll
            for (int e = 0; e < 4; e++) {
                int d = gld + e;
                int sd = 4 * ((d >> 3) & 7);
                Ks[d * 64 + (klocal[rep] ^ sd)] = kv[e];
            }
        }
    };
    auto writeV = [&]() {
        #pragma unroll
        for (int rep = 0; rep < 4; rep++)
            *(float4*)&Vs[klocal[rep] * 64 + gld] = vreg[rep];
    };

    gather(0); writeK(); writeV();
    __syncthreads();

    float m[8], l[8], acc[8][8];
    #pragma unroll
    for (int r = 0; r < 8; r++) {
        m[r] = -INFINITY; l[r] = 0.f;
        #pragma unroll
        for (int c = 0; c < 8; c++) acc[r][c] = 0.f;
    }

    for (int t = 0; t < NT; t++) {
        const bool pf = (t + 1 < NT);
        if (pf) gather(t + 1);   // loads in flight through QK phase

        // ---- S = Q K^T  (8x8 per thread) ----
        float s[8][8];
        #pragma unroll
        for (int r = 0; r < 8; r++)
            #pragma unroll
            for (int c = 0; c < 8; c++) s[r][c] = 0.f;
        #pragma unroll 2
        for (int d = 0; d < 64; d++) {
            int sd = 4 * ((d >> 3) & 7);
            float4 qa = *(float4*)&Qs[d * 256 + ((rg * 8) ^ sd)];
            float4 qb = *(float4*)&Qs[d * 256 + ((rg * 8 + 4) ^ sd)];
            float4 ka = *(float4*)&Ks[d * 64 + ((kg * 8) ^ sd)];
            float4 kb = *(float4*)&Ks[d * 64 + ((kg * 8 + 4) ^ sd)];
            float qv[8] = {qa.x, qa.y, qa.z, qa.w, qb.x, qb.y, qb.z, qb.w};
            float kv[8] = {ka.x, ka.y, ka.z, ka.w, kb.x, kb.y, kb.z, kb.w};
            #pragma unroll
            for (int r = 0; r < 8; r++)
                #pragma unroll
                for (int c = 0; c < 8; c++) s[r][c] += qv[r] * kv[c];
        }

        // ---- online softmax (row r owned by 8 lanes sharing rg) ----
        float corr[8];
        #pragma unroll
        for (int r = 0; r < 8; r++) {
            float rm = s[r][0];
            #pragma unroll
            for (int c = 1; c < 8; c++) rm = fmaxf(rm, s[r][c]);
            rm = fmaxf(rm, __shfl_xor(rm, 1));
            rm = fmaxf(rm, __shfl_xor(rm, 2));
            rm = fmaxf(rm, __shfl_xor(rm, 4));
            float mn = fmaxf(m[r], rm);
            corr[r] = __expf(m[r] - mn);
            m[r] = mn;
            float rs = 0.f;
            #pragma unroll
            for (int c = 0; c < 8; c++) { float p = __expf(s[r][c] - mn); s[r][c] = p; rs += p; }
            rs += __shfl_xor(rs, 1);
            rs += __shfl_xor(rs, 2);
            rs += __shfl_xor(rs, 4);
            l[r] = l[r] * corr[r] + rs;
        }

        __syncthreads();  // A: all QK reads of Ks(t) + PV(t-1) reads of Ps done

        // P write: transposed [k][r], swizzled, b128
        {
            int sdp = 4 * kg;
            #pragma unroll
            for (int c = 0; c < 8; c++) {
                float4 w0 = make_float4(s[0][c], s[1][c], s[2][c], s[3][c]);
                float4 w1 = make_float4(s[4][c], s[5][c], s[6][c], s[7][c]);
                *(float4*)&Ps[(kg * 8 + c) * 256 + ((rg * 8) ^ sdp)] = w0;
                *(float4*)&Ps[(kg * 8 + c) * 256 + ((rg * 8 + 4) ^ sdp)] = w1;
            }
        }
        if (pf) writeK();  // Ks(t+1); safe: QK(t) reads finished at A

        // rescale accumulators
        #pragma unroll
        for (int r = 0; r < 8; r++)
            #pragma unroll
            for (int c = 0; c < 8; c++) acc[r][c] *= corr[r];

        __syncthreads();  // B: Ps(t) + Ks(t+1) visible

        // ---- O += P V  (8 rows x 8 d per thread) ----
        #pragma unroll 2
        for (int k = 0; k < 64; k++) {
            int sdp = 4 * ((k >> 3) & 7);
            float4 pa = *(float4*)&Ps[k * 256 + ((rg * 8) ^ sdp)];
            float4 pb = *(float4*)&Ps[k * 256 + ((rg * 8 + 4) ^ sdp)];
            float4 va = *(float4*)&Vs[k * 64 + kg * 8];
            float4 vb = *(float4*)&Vs[k * 64 + kg * 8 + 4];
            float pv[8] = {pa.x, pa.y, pa.z, pa.w, pb.x, pb.y, pb.z, pb.w};
            float vv[8] = {va.x, va.y, va.z, va.w, vb.x, vb.y, vb.z, vb.w};
            #pragma unroll
            for (int r = 0; r < 8; r++)
                #pragma unroll
                for (int c = 0; c < 8; c++) acc[r][c] += pv[r] * vv[c];
        }

        __syncthreads();  // C: PV reads of Vs(t)/Ps(t) done
        if (pf) writeV();  // Vs(t+1); read next iter after barriers A/B
    }

    // ---- epilogue: normalize + write O row-major ----
    const int orow0 = n * T_DIM + qt * QT + rg * 8;
    const int ocol = h * HD + kg * 8;
    #pragma unroll
    for (int r = 0; r < 8; r++) {
        float inv = 1.0f / l[r];
        float4 o0 = make_float4(acc[r][0] * inv, acc[r][1] * inv,
                                acc[r][2] * inv, acc[r][3] * inv);
        float4 o1 = make_float4(acc[r][4] * inv, acc[r][5] * inv,
                                acc[r][6] * inv, acc[r][7] * inv);
        float* p = Og + (size_t)(orow0 + r) * C_DIM + ocol;
        *(float4*)p = o0;
        *(float4*)(p + 4) = o1;
    }
}

// ---------------------------------------------------------------------------
// Kernel 3: output projection + bias + residual (unchanged).
// ---------------------------------------------------------------------------
__global__ __launch_bounds__(256) void out_gemm(
    const float* __restrict__ A, const float* __restrict__ W,
    const float* __restrict__ bias, const float* __restrict__ X,
    float* __restrict__ Out)
{
    __shared__ float As[16][132];
    __shared__ float Bs[16][132];
    const int tid = threadIdx.x;
    const int tx = tid & 15, ty = tid >> 4;
    const int cW = blockIdx.x * 128;
    const int r0 = blockIdx.y * 128;

    float acc[2][2][4][4];
    #pragma unroll
    for (int a = 0; a < 2; a++)
        #pragma unroll
        for (int b = 0; b < 2; b++)
            #pragma unroll
            for (int i = 0; i < 4; i++)
                #pragma unroll
                for (int j = 0; j < 4; j++) acc[a][b][i][j] = 0.f;

    for (int kk = 0; kk < C_DIM; kk += 16) {
        #pragma unroll
        for (int rep = 0; rep < 2; rep++) {
            int flat = rep * 256 + tid;
            int row = flat >> 2, ch = flat & 3;
            float4 v = *(const float4*)(A + (size_t)(r0 + row) * C_DIM + kk + ch * 4);
            As[ch * 4 + 0][row] = v.x;
            As[ch * 4 + 1][row] = v.y;
            As[ch * 4 + 2][row] = v.z;
            As[ch * 4 + 3][row] = v.w;
        }
        #pragma unroll
        for (int rep = 0; rep < 2; rep++) {
            int flat = rep * 256 + tid;
            int row = flat >> 5, ch = flat & 31;
            *(float4*)&Bs[row][ch * 4] =
                *(const float4*)(W + (size_t)(kk + row) * C_DIM + cW + ch * 4);
        }
        __syncthreads();
        #pragma unroll
        for (int k = 0; k < 16; k++) {
            float4 a0 = *(float4*)&As[k][ty * 4];
            float4 a1 = *(float4*)&As[k][64 + ty * 4];
            float4 b0 = *(float4*)&Bs[k][tx * 4];
            float4 b1 = *(float4*)&Bs[k][64 + tx * 4];
            float av[2][4] = {{a0.x, a0.y, a0.z, a0.w}, {a1.x, a1.y, a1.z, a1.w}};
            float bv[2][4] = {{b0.x, b0.y, b0.z, b0.w}, {b1.x, b1.y, b1.z, b1.w}};
            #pragma unroll
            for (int p = 0; p < 2; p++)
                #pragma unroll
                for (int q = 0; q < 4; q++)
                    #pragma unroll
                    for (int u = 0; u < 2; u++)
                        #pragma unroll
                        for (int w = 0; w < 4; w++)
                            acc[p][u][q][w] += av[p][q] * bv[u][w];
        }
        __syncthreads();
    }
    #pragma unroll
    for (int rb = 0; rb < 2; rb++)
        #pragma unroll
        for (int rr = 0; rr < 4; rr++) {
            int r = r0 + rb * 64 + ty * 4 + rr;
            #pragma unroll
            for (int cb = 0; cb < 2; cb++) {
                int c = cW + cb * 64 + tx * 4;
                float4 bv = *(const float4*)(bias + c);
                float4 xv = *(const float4*)(X + (size_t)r * C_DIM + c);
                float4 v = make_float4(acc[rb][cb][rr][0] + bv.x + xv.x,
                                       acc[rb][cb][rr][1] + bv.y + xv.y,
                                       acc[rb][cb][rr][2] + bv.z + xv.z,
                                       acc[rb][cb][rr][3] + bv.w + xv.w);
                *(float4*)(Out + (size_t)r * C_DIM + c) = v;
            }
        }
}

extern "C" void kernel_launch(void* const* d_in, const int* in_sizes, int n_in,
                              void* d_out, int out_size, void* d_ws, size_t ws_size,
                              hipStream_t stream) {
    const float* X  = (const float*)d_in[0];
    const int* idx  = (const int*)d_in[1];
    const float* Wq = (const float*)d_in[2];
    const float* Wk = (const float*)d_in[3];
    const float* Wv = (const float*)d_in[4];
    const float* Wo = (const float*)d_in[5];
    const float* bo = (const float*)d_in[6];
    // d_in[7] = heads (20), hard-coded

    float* ws = (float*)d_ws;
    const size_t SZ = (size_t)MROWS * C_DIM;  // 13,107,200 floats
    float* Q = ws;
    float* K = ws + SZ;
    float* V = ws + 2 * SZ;
    float* O = ws + 3 * SZ;

    dim3 g1(30, 80);
    qkv_gemm<<<g1, 256, 0, stream>>>(X, Wq, Wk, Wv, Q, K, V);
    dim3 g2(T_DIM / QT, HEADS, 10);
    flash_attn<<<g2, 256, 0, stream>>>(Q, K, V, idx, O);
    dim3 g3(10, 80);
    out_gemm<<<g3, 256, 0, stream>>>(O, Wo, bo, X, (float*)d_out);
}

// Round 4
// 2239.570 us; speedup vs baseline: 2.3592x; 2.3592x over previous
//
#include <hip/hip_runtime.h>
#include <math.h>

#define C_DIM 1280
#define T_DIM 1024
#define NIMG 5
#define HEADS 20
#define HD 64
#define NSEL 512
#define MROWS (10 * T_DIM)      // 10240
#define SCTX (4 * NSEL + T_DIM) // 3072
#define KT 64
#define NT (SCTX / KT)          // 48

typedef __attribute__((ext_vector_type(8))) short short8v;
typedef __attribute__((ext_vector_type(4))) short short4v;
typedef __attribute__((ext_vector_type(4))) float float4v;

// f32 -> bf16 round-to-nearest-even, bit pattern as short
static __device__ __forceinline__ short f2bf(float f) {
    union { float f; unsigned u; } v; v.f = f;
    unsigned r = (v.u + 0x7FFFu + ((v.u >> 16) & 1u)) >> 16;
    return (short)r;
}

// ---------------------------------------------------------------------------
// Kernel 1: fused QKV projection GEMM (unchanged; near f32 vector roofline).
// ---------------------------------------------------------------------------
__global__ __launch_bounds__(256) void qkv_gemm(
    const float* __restrict__ X, const float* __restrict__ Wq,
    const float* __restrict__ Wk, const float* __restrict__ Wv,
    float* __restrict__ Qo, float* __restrict__ Ko, float* __restrict__ Vo)
{
    __shared__ float As[16][132];
    __shared__ float Bs[16][132];
    const int tid = threadIdx.x;
    const int tx = tid & 15, ty = tid >> 4;
    const int bn = blockIdx.x;
    const int bm = blockIdx.y;
    const int wsel = bn / 10;
    const int cW = (bn - wsel * 10) * 128;
    const float* __restrict__ W = (wsel == 0) ? Wq : (wsel == 1) ? Wk : Wv;
    float* __restrict__ Out = (wsel == 0) ? Qo : (wsel == 1) ? Ko : Vo;
    const int r0 = bm * 128;

    float acc[2][2][4][4];
    #pragma unroll
    for (int a = 0; a < 2; a++)
        #pragma unroll
        for (int b = 0; b < 2; b++)
            #pragma unroll
            for (int i = 0; i < 4; i++)
                #pragma unroll
                for (int j = 0; j < 4; j++) acc[a][b][i][j] = 0.f;

    for (int kk = 0; kk < C_DIM; kk += 16) {
        #pragma unroll
        for (int rep = 0; rep < 2; rep++) {
            int flat = rep * 256 + tid;
            int row = flat >> 2, ch = flat & 3;
            float4 v = *(const float4*)(X + (size_t)(r0 + row) * C_DIM + kk + ch * 4);
            As[ch * 4 + 0][row] = v.x;
            As[ch * 4 + 1][row] = v.y;
            As[ch * 4 + 2][row] = v.z;
            As[ch * 4 + 3][row] = v.w;
        }
        #pragma unroll
        for (int rep = 0; rep < 2; rep++) {
            int flat = rep * 256 + tid;
            int row = flat >> 5, ch = flat & 31;
            *(float4*)&Bs[row][ch * 4] =
                *(const float4*)(W + (size_t)(kk + row) * C_DIM + cW + ch * 4);
        }
        __syncthreads();
        #pragma unroll
        for (int k = 0; k < 16; k++) {
            float4 a0 = *(float4*)&As[k][ty * 4];
            float4 a1 = *(float4*)&As[k][64 + ty * 4];
            float4 b0 = *(float4*)&Bs[k][tx * 4];
            float4 b1 = *(float4*)&Bs[k][64 + tx * 4];
            float av[2][4] = {{a0.x, a0.y, a0.z, a0.w}, {a1.x, a1.y, a1.z, a1.w}};
            float bv[2][4] = {{b0.x, b0.y, b0.z, b0.w}, {b1.x, b1.y, b1.z, b1.w}};
            #pragma unroll
            for (int p = 0; p < 2; p++)
                #pragma unroll
                for (int q = 0; q < 4; q++)
                    #pragma unroll
                    for (int u = 0; u < 2; u++)
                        #pragma unroll
                        for (int w = 0; w < 4; w++)
                            acc[p][u][q][w] += av[p][q] * bv[u][w];
        }
        __syncthreads();
    }
    #pragma unroll
    for (int rb = 0; rb < 2; rb++)
        #pragma unroll
        for (int rr = 0; rr < 4; rr++) {
            int r = r0 + rb * 64 + ty * 4 + rr;
            int n = r >> 10, t = r & 1023;
            #pragma unroll
            for (int cb = 0; cb < 2; cb++) {
                int c = cW + cb * 64 + tx * 4;
                int h = c >> 6, d = c & 63;
                float4 v = make_float4(acc[rb][cb][rr][0], acc[rb][cb][rr][1],
                                       acc[rb][cb][rr][2], acc[rb][cb][rr][3]);
                *(float4*)(Out + ((size_t)((n * HEADS + h) * T_DIM + t)) * HD + d) = v;
            }
        }
}

// ---------------------------------------------------------------------------
// Kernel 2: flash attention, bf16 MFMA (16x16x32), f32 softmax.
// 512 threads = 8 waves; wave w owns q-rows [qb + w*16, +16).
// Per k-tile (64 ctx rows): QK = 4 k16-subtiles x 2 d-halves = 8 mfma;
// PV = 2 k-chunks x 4 d16 = 8 mfma. Q A-frags in registers (whole kernel).
// LDS: Ks[64][72] bf16 row-major, Vt[64][72] bf16 transposed+XOR-swizzled,
// Ps per-wave [16][72] bf16 (no barrier; lgkmcnt fence). 36KB total.
// K/V(t+1) gathered to regs during compute, stored after tile barrier.
// ---------------------------------------------------------------------------
__global__ __launch_bounds__(512) void attn_mfma(
    const float* __restrict__ Qg, const float* __restrict__ Kg,
    const float* __restrict__ Vg, const int* __restrict__ idxg,
    float* __restrict__ Og)
{
    __shared__ __align__(16) short Ks[64 * 72];
    __shared__ __align__(16) short Vt[64 * 72];
    __shared__ __align__(16) short Ps[8 * 16 * 72];

    const int tid = threadIdx.x;
    const int lane = tid & 63;
    const int wv = tid >> 6;          // wave 0..7
    const int lc = lane & 15;         // matrix-major index within frags
    const int lg = lane >> 4;         // k-group 0..3
    const int qb = blockIdx.x * 128;  // q window base
    const int h = blockIdx.y, n = blockIdx.z;
    const int b = n / NIMG, i = n - b * NIMG;
    int jl[4];
    { int c = 0; for (int j = 0; j < NIMG; j++) if (j != i) jl[c++] = j; }

    // ---- Q A-fragments (held in registers all kernel), pre-scaled ----
    short8v qfrag[2];
    {
        const float* qrow = Qg + ((size_t)(n * HEADS + h) * T_DIM + (qb + wv * 16 + lc)) * HD;
        #pragma unroll
        for (int dh = 0; dh < 2; dh++) {
            float4 a = *(const float4*)(qrow + dh * 32 + lg * 8);
            float4 bq = *(const float4*)(qrow + dh * 32 + lg * 8 + 4);
            short8v f;
            f[0] = f2bf(a.x * 0.125f);  f[1] = f2bf(a.y * 0.125f);
            f[2] = f2bf(a.z * 0.125f);  f[3] = f2bf(a.w * 0.125f);
            f[4] = f2bf(bq.x * 0.125f); f[5] = f2bf(bq.y * 0.125f);
            f[6] = f2bf(bq.z * 0.125f); f[7] = f2bf(bq.w * 0.125f);
            qfrag[dh] = f;
        }
    }

    // ---- staging mapping: 512 threads cover 64 rows x 64 d (f32) ----
    const int srow = tid >> 3;        // ctx-local row 0..63
    const int sc4 = (tid & 7) * 4;    // d base (two float4s: sc4, 32+sc4)
    float4 fk0, fk1, fv0, fv1;

    auto ctxbase = [&](int cr) -> size_t {
        int j, st;
        if (cr < 4 * NSEL) { j = jl[cr >> 9]; st = idxg[j * NSEL + (cr & (NSEL - 1))]; }
        else               { j = i;           st = cr - 4 * NSEL; }
        return (((size_t)(b * NIMG + j) * HEADS + h) * T_DIM + st) * (size_t)HD;
    };
    auto gatherK = [&](int t) {
        size_t base = ctxbase(t * KT + srow);
        fk0 = *(const float4*)(Kg + base + sc4);
        fk1 = *(const float4*)(Kg + base + 32 + sc4);
    };
    auto gatherV = [&](int t) {
        size_t base = ctxbase(t * KT + srow);
        fv0 = *(const float4*)(Vg + base + sc4);
        fv1 = *(const float4*)(Vg + base + 32 + sc4);
    };
    auto writeK = [&]() {
        short4v w0 = { f2bf(fk0.x), f2bf(fk0.y), f2bf(fk0.z), f2bf(fk0.w) };
        short4v w1 = { f2bf(fk1.x), f2bf(fk1.y), f2bf(fk1.z), f2bf(fk1.w) };
        *(short4v*)&Ks[srow * 72 + sc4] = w0;
        *(short4v*)&Ks[srow * 72 + 32 + sc4] = w1;
    };
    auto writeVt = [&]() {
        float v0[4] = { fv0.x, fv0.y, fv0.z, fv0.w };
        float v1[4] = { fv1.x, fv1.y, fv1.z, fv1.w };
        #pragma unroll
        for (int e = 0; e < 4; e++) {
            int d0 = sc4 + e;
            int d1 = 32 + sc4 + e;
            Vt[d0 * 72 + (srow ^ (((d0 >> 3) & 7) << 3))] = f2bf(v0[e]);
            Vt[d1 * 72 + (srow ^ (((d1 >> 3) & 7) << 3))] = f2bf(v1[e]);
        }
    };

    float4v o[4];
    float mrow[4], lrow[4];
    #pragma unroll
    for (int d16 = 0; d16 < 4; d16++) o[d16] = (float4v){0.f, 0.f, 0.f, 0.f};
    #pragma unroll
    for (int r = 0; r < 4; r++) { mrow[r] = -INFINITY; lrow[r] = 0.f; }

    const int pw = wv * 16 * 72;  // per-wave P region

    gatherK(0); gatherV(0);

    for (int t = 0; t < NT; t++) {
        writeK(); writeVt();
        __syncthreads();                      // B1: K/V(t) visible
        if (t + 1 < NT) gatherK(t + 1);       // prefetch K in flight over QK

        // ---- S = Q K^T : 4 k16-subtiles, accumulate over 2 d-halves ----
        float4v s[4];
        #pragma unroll
        for (int k16 = 0; k16 < 4; k16++) {
            float4v z = {0.f, 0.f, 0.f, 0.f};
            #pragma unroll
            for (int dh = 0; dh < 2; dh++) {
                short8v bf = *(const short8v*)&Ks[(k16 * 16 + lc) * 72 + dh * 32 + lg * 8];
                z = __builtin_amdgcn_mfma_f32_16x16x32_bf16(qfrag[dh], bf, z, 0, 0, 0);
            }
            s[k16] = z;
        }

        // ---- online softmax (rows lg*4+r, replicated over 16 lc lanes) ----
        float corr[4];
        #pragma unroll
        for (int r = 0; r < 4; r++) {
            float lm = fmaxf(fmaxf(s[0][r], s[1][r]), fmaxf(s[2][r], s[3][r]));
            lm = fmaxf(lm, __shfl_xor(lm, 1));
            lm = fmaxf(lm, __shfl_xor(lm, 2));
            lm = fmaxf(lm, __shfl_xor(lm, 4));
            lm = fmaxf(lm, __shfl_xor(lm, 8));
            float mn = fmaxf(mrow[r], lm);
            corr[r] = __expf(mrow[r] - mn);
            mrow[r] = mn;
            float p0 = __expf(s[0][r] - mn);
            float p1 = __expf(s[1][r] - mn);
            float p2 = __expf(s[2][r] - mn);
            float p3 = __expf(s[3][r] - mn);
            s[0][r] = p0; s[1][r] = p1; s[2][r] = p2; s[3][r] = p3;
            float rs = p0 + p1 + p2 + p3;
            rs += __shfl_xor(rs, 1);
            rs += __shfl_xor(rs, 2);
            rs += __shfl_xor(rs, 4);
            rs += __shfl_xor(rs, 8);
            lrow[r] = lrow[r] * corr[r] + rs;
        }

        // ---- P -> bf16 into per-wave LDS (A-layout source) ----
        #pragma unroll
        for (int k16 = 0; k16 < 4; k16++)
            #pragma unroll
            for (int r = 0; r < 4; r++)
                Ps[pw + (lg * 4 + r) * 72 + k16 * 16 + lc] = f2bf(s[k16][r]);
        asm volatile("s_waitcnt lgkmcnt(0)" ::: "memory");  // P committed (same-wave reads below)
        __builtin_amdgcn_sched_barrier(0);

        if (t + 1 < NT) gatherV(t + 1);       // prefetch V in flight over PV

        // rescale O accumulators
        #pragma unroll
        for (int d16 = 0; d16 < 4; d16++)
            #pragma unroll
            for (int r = 0; r < 4; r++) o[d16][r] *= corr[r];

        // ---- O += P V : 2 k-chunks x 4 d16 ----
        #pragma unroll
        for (int kch = 0; kch < 2; kch++) {
            short8v pa = *(const short8v*)&Ps[pw + lc * 72 + kch * 32 + lg * 8];
            #pragma unroll
            for (int d16 = 0; d16 < 4; d16++) {
                int d = d16 * 16 + lc;
                int xk = ((d >> 3) & 7) << 3;
                short8v vb = *(const short8v*)&Vt[d * 72 + ((kch * 32 + lg * 8) ^ xk)];
                o[d16] = __builtin_amdgcn_mfma_f32_16x16x32_bf16(pa, vb, o[d16], 0, 0, 0);
            }
        }

        __syncthreads();                      // B2: all reads of K/V(t) done
    }

    // ---- epilogue: normalize, write O (row-major MROWS x C_DIM) ----
    #pragma unroll
    for (int r = 0; r < 4; r++) {
        float inv = 1.0f / lrow[r];
        size_t row = (size_t)(n * T_DIM + qb + wv * 16 + lg * 4 + r) * C_DIM + h * HD;
        #pragma unroll
        for (int d16 = 0; d16 < 4; d16++)
            Og[row + d16 * 16 + lc] = o[d16][r] * inv;
    }
}

// ---------------------------------------------------------------------------
// Kernel 3: output projection + bias + residual (unchanged).
// ---------------------------------------------------------------------------
__global__ __launch_bounds__(256) void out_gemm(
    const float* __restrict__ A, const float* __restrict__ W,
    const float* __restrict__ bias, const float* __restrict__ X,
    float* __restrict__ Out)
{
    __shared__ float As[16][132];
    __shared__ float Bs[16][132];
    const int tid = threadIdx.x;
    const int tx = tid & 15, ty = tid >> 4;
    const int cW = blockIdx.x * 128;
    const int r0 = blockIdx.y * 128;

    float acc[2][2][4][4];
    #pragma unroll
    for (int a = 0; a < 2; a++)
        #pragma unroll
        for (int b = 0; b < 2; b++)
            #pragma unroll
            for (int i = 0; i < 4; i++)
                #pragma unroll
                for (int j = 0; j < 4; j++) acc[a][b][i][j] = 0.f;

    for (int kk = 0; kk < C_DIM; kk += 16) {
        #pragma unroll
        for (int rep = 0; rep < 2; rep++) {
            int flat = rep * 256 + tid;
            int row = flat >> 2, ch = flat & 3;
            float4 v = *(const float4*)(A + (size_t)(r0 + row) * C_DIM + kk + ch * 4);
            As[ch * 4 + 0][row] = v.x;
            As[ch * 4 + 1][row] = v.y;
            As[ch * 4 + 2][row] = v.z;
            As[ch * 4 + 3][row] = v.w;
        }
        #pragma unroll
        for (int rep = 0; rep < 2; rep++) {
            int flat = rep * 256 + tid;
            int row = flat >> 5, ch = flat & 31;
            *(float4*)&Bs[row][ch * 4] =
                *(const float4*)(W + (size_t)(kk + row) * C_DIM + cW + ch * 4);
        }
        __syncthreads();
        #pragma unroll
        for (int k = 0; k < 16; k++) {
            float4 a0 = *(float4*)&As[k][ty * 4];
            float4 a1 = *(float4*)&As[k][64 + ty * 4];
            float4 b0 = *(float4*)&Bs[k][tx * 4];
            float4 b1 = *(float4*)&Bs[k][64 + tx * 4];
            float av[2][4] = {{a0.x, a0.y, a0.z, a0.w}, {a1.x, a1.y, a1.z, a1.w}};
            float bv[2][4] = {{b0.x, b0.y, b0.z, b0.w}, {b1.x, b1.y, b1.z, b1.w}};
            #pragma unroll
            for (int p = 0; p < 2; p++)
                #pragma unroll
                for (int q = 0; q < 4; q++)
                    #pragma unroll
                    for (int u = 0; u < 2; u++)
                        #pragma unroll
                        for (int w = 0; w < 4; w++)
                            acc[p][u][q][w] += av[p][q] * bv[u][w];
        }
        __syncthreads();
    }
    #pragma unroll
    for (int rb = 0; rb < 2; rb++)
        #pragma unroll
        for (int rr = 0; rr < 4; rr++) {
            int r = r0 + rb * 64 + ty * 4 + rr;
            #pragma unroll
            for (int cb = 0; cb < 2; cb++) {
                int c = cW + cb * 64 + tx * 4;
                float4 bv = *(const float4*)(bias + c);
                float4 xv = *(const float4*)(X + (size_t)r * C_DIM + c);
                float4 v = make_float4(acc[rb][cb][rr][0] + bv.x + xv.x,
                                       acc[rb][cb][rr][1] + bv.y + xv.y,
                                       acc[rb][cb][rr][2] + bv.z + xv.z,
                                       acc[rb][cb][rr][3] + bv.w + xv.w);
                *(float4*)(Out + (size_t)r * C_DIM + c) = v;
            }
        }
}

extern "C" void kernel_launch(void* const* d_in, const int* in_sizes, int n_in,
                              void* d_out, int out_size, void* d_ws, size_t ws_size,
                              hipStream_t stream) {
    const float* X  = (const float*)d_in[0];
    const int* idx  = (const int*)d_in[1];
    const float* Wq = (const float*)d_in[2];
    const float* Wk = (const float*)d_in[3];
    const float* Wv = (const float*)d_in[4];
    const float* Wo = (const float*)d_in[5];
    const float* bo = (const float*)d_in[6];
    // d_in[7] = heads (20), hard-coded

    float* ws = (float*)d_ws;
    const size_t SZ = (size_t)MROWS * C_DIM;  // 13,107,200 floats
    float* Q = ws;
    float* K = ws + SZ;
    float* V = ws + 2 * SZ;
    float* O = ws + 3 * SZ;

    dim3 g1(30, 80);
    qkv_gemm<<<g1, 256, 0, stream>>>(X, Wq, Wk, Wv, Q, K, V);
    dim3 g2(T_DIM / 128, HEADS, 10);
    attn_mfma<<<g2, 512, 0, stream>>>(Q, K, V, idx, O);
    dim3 g3(10, 80);
    out_gemm<<<g3, 256, 0, stream>>>(O, Wo, bo, X, (float*)d_out);
}

// Round 5
// 860.450 us; speedup vs baseline: 6.1406x; 2.6028x over previous
//
#include <hip/hip_runtime.h>
#include <math.h>

#define C_DIM 1280
#define T_DIM 1024
#define NIMG 5
#define HEADS 20
#define HD 64
#define NSEL 512
#define MROWS (10 * T_DIM)      // 10240
#define SCTX (4 * NSEL + T_DIM) // 3072
#define KT 64
#define NT (SCTX / KT)          // 48

typedef unsigned short ushortT;
typedef __attribute__((ext_vector_type(8))) short short8v;
typedef __attribute__((ext_vector_type(4))) short short4v;
typedef __attribute__((ext_vector_type(4))) float float4v;

// f32 -> bf16 round-to-nearest-even, bit pattern as ushort
static __device__ __forceinline__ ushortT f2bf(float f) {
    union { float f; unsigned u; } v; v.f = f;
    unsigned r = (v.u + 0x7FFFu + ((v.u >> 16) & 1u)) >> 16;
    return (ushortT)r;
}

// ---------------------------------------------------------------------------
// Prep 1: X f32 -> bf16 row-major [M][K]
// ---------------------------------------------------------------------------
__global__ __launch_bounds__(256) void cvt_x(const float* __restrict__ X,
                                             ushortT* __restrict__ Xbf)
{
    int i = (blockIdx.x * 256 + threadIdx.x) * 4;
    float4 v = *(const float4*)(X + i);
    short4v o = { (short)f2bf(v.x), (short)f2bf(v.y), (short)f2bf(v.z), (short)f2bf(v.w) };
    *(short4v*)(Xbf + i) = o;
}

// ---------------------------------------------------------------------------
// Prep 2: W[z] (k x n f32) -> Wbf[z] (n x k bf16), z in {q,k,v,o}
// ---------------------------------------------------------------------------
__global__ __launch_bounds__(256) void cvt_w(
    const float* __restrict__ Wq, const float* __restrict__ Wk,
    const float* __restrict__ Wv, const float* __restrict__ Wo,
    ushortT* __restrict__ Wbf)
{
    __shared__ float t[32][33];
    const int z = blockIdx.z;
    const float* __restrict__ W = (z == 0) ? Wq : (z == 1) ? Wk : (z == 2) ? Wv : Wo;
    const int nt = blockIdx.x * 32, kt = blockIdx.y * 32;
    const int x = threadIdx.x & 31, y = threadIdx.x >> 5;
    #pragma unroll
    for (int r = 0; r < 4; r++)
        t[y + r * 8][x] = W[(size_t)(kt + y + r * 8) * C_DIM + nt + x];
    __syncthreads();
    ushortT* __restrict__ Wz = Wbf + (size_t)z * C_DIM * C_DIM;
    #pragma unroll
    for (int r = 0; r < 4; r++)
        Wz[(size_t)(nt + y + r * 8) * C_DIM + kt + x] = f2bf(t[x][y + r * 8]);
}

// ---------------------------------------------------------------------------
// MFMA GEMM: C(128x128 per block) = A(row-major [M][K] bf16) x W^T([n][k] bf16).
// 256 thr = 4 waves (2x2 of 64x64); 16x16x32 bf16 mfma; BK=64; reg-staged with
// T14 issue-early; LDS chunk-swizzle cslot = chunk ^ (row&7) (linear writes,
// <=2-way reads). MODE 0: qkv scatter to [n][h][t][d] bf16 (Q pre-scaled 1/8).
// MODE 1: out = acc + bias + residual, f32 row-major.
// ---------------------------------------------------------------------------
template<int MODE>
__global__ __launch_bounds__(256) void mfma_gemm(
    const ushortT* __restrict__ Abf, const ushortT* __restrict__ Wbf,
    ushortT* __restrict__ Qo, ushortT* __restrict__ Ko, ushortT* __restrict__ Vo,
    const float* __restrict__ bias, const float* __restrict__ Xres,
    float* __restrict__ Out)
{
    __shared__ __align__(16) ushortT As[128 * 64];
    __shared__ __align__(16) ushortT Bs[128 * 64];
    const int tid = threadIdx.x;
    const int lane = tid & 63, wv = tid >> 6;
    const int lc = lane & 15, lg = lane >> 4;
    const int wr = wv >> 1, wc = wv & 1;
    int wsel, cb;
    if (MODE == 0) { wsel = blockIdx.x / 10; cb = blockIdx.x % 10; }
    else           { wsel = 0;              cb = blockIdx.x; }
    const int r0 = blockIdx.y * 128, c0 = cb * 128;
    const ushortT* __restrict__ A0 = Abf + (size_t)r0 * C_DIM;
    const ushortT* __restrict__ B0 = Wbf + (size_t)wsel * C_DIM * C_DIM + (size_t)c0 * C_DIM;

    // staging map: pass p covers chunk idx = p*256+tid; linear LDS, XOR'd global
    int g_off[4], l_off[4];
    #pragma unroll
    for (int p = 0; p < 4; p++) {
        int idx = p * 256 + tid;
        int row = idx >> 3, cslot = idx & 7;
        int csrc = cslot ^ (row & 7);
        g_off[p] = row * C_DIM + csrc * 8;
        l_off[p] = row * 64 + cslot * 8;  // == idx*8 (linear)
    }
    short8v Ar[4], Br[4];

    float4v acc[4][4];
    #pragma unroll
    for (int mi = 0; mi < 4; mi++)
        #pragma unroll
        for (int ni = 0; ni < 4; ni++) acc[mi][ni] = (float4v){0.f, 0.f, 0.f, 0.f};

    #pragma unroll
    for (int p = 0; p < 4; p++) {
        Ar[p] = *(const short8v*)(A0 + g_off[p]);
        Br[p] = *(const short8v*)(B0 + g_off[p]);
    }

    for (int kk = 0; kk < C_DIM; kk += 64) {
        __syncthreads();                 // prev compute readers done
        #pragma unroll
        for (int p = 0; p < 4; p++) {
            *(short8v*)&As[l_off[p]] = Ar[p];
            *(short8v*)&Bs[l_off[p]] = Br[p];
        }
        __syncthreads();                 // tile visible
        if (kk + 64 < C_DIM) {           // issue next loads; land during compute
            #pragma unroll
            for (int p = 0; p < 4; p++) {
                Ar[p] = *(const short8v*)(A0 + g_off[p] + kk + 64);
                Br[p] = *(const short8v*)(B0 + g_off[p] + kk + 64);
            }
        }
        #pragma unroll
        for (int dh = 0; dh < 2; dh++) {
            short8v af[4], bf[4];
            const int cslot = ((dh * 4 + lg) ^ (lc & 7)) * 8;
            #pragma unroll
            for (int mi = 0; mi < 4; mi++)
                af[mi] = *(const short8v*)&As[(wr * 64 + mi * 16 + lc) * 64 + cslot];
            #pragma unroll
            for (int ni = 0; ni < 4; ni++)
                bf[ni] = *(const short8v*)&Bs[(wc * 64 + ni * 16 + lc) * 64 + cslot];
            #pragma unroll
            for (int mi = 0; mi < 4; mi++)
                #pragma unroll
                for (int ni = 0; ni < 4; ni++)
                    acc[mi][ni] = __builtin_amdgcn_mfma_f32_16x16x32_bf16(
                        af[mi], bf[ni], acc[mi][ni], 0, 0, 0);
        }
    }

    if (MODE == 0) {
        ushortT* __restrict__ OutW = (wsel == 0) ? Qo : (wsel == 1) ? Ko : Vo;
        const float scale = (wsel == 0) ? 0.125f : 1.0f;
        #pragma unroll
        for (int mi = 0; mi < 4; mi++)
            #pragma unroll
            for (int reg = 0; reg < 4; reg++) {
                int row = r0 + wr * 64 + mi * 16 + lg * 4 + reg;
                int nimg = row >> 10, t = row & 1023;
                #pragma unroll
                for (int ni = 0; ni < 4; ni++) {
                    int col = c0 + wc * 64 + ni * 16 + lc;
                    int hh = col >> 6, d = col & 63;
                    OutW[((size_t)(nimg * HEADS + hh) * T_DIM + t) * HD + d] =
                        f2bf(acc[mi][ni][reg] * scale);
                }
            }
    } else {
        #pragma unroll
        for (int mi = 0; mi < 4; mi++)
            #pragma unroll
            for (int reg = 0; reg < 4; reg++) {
                int row = r0 + wr * 64 + mi * 16 + lg * 4 + reg;
                #pragma unroll
                for (int ni = 0; ni < 4; ni++) {
                    int col = c0 + wc * 64 + ni * 16 + lc;
                    size_t o = (size_t)row * C_DIM + col;
                    Out[o] = acc[mi][ni][reg] + bias[col] + Xres[o];
                }
            }
    }
}

// ---------------------------------------------------------------------------
// Flash attention, bf16 MFMA (16x16x32), f32 softmax. Structure unchanged from
// round 4 (passed); I/O now bf16. Q pre-scaled by 1/8 in qkv epilogue.
// ---------------------------------------------------------------------------
__global__ __launch_bounds__(512) void attn_mfma(
    const ushortT* __restrict__ Qg, const ushortT* __restrict__ Kg,
    const ushortT* __restrict__ Vg, const int* __restrict__ idxg,
    ushortT* __restrict__ Og)
{
    __shared__ __align__(16) ushortT Ks[64 * 72];
    __shared__ __align__(16) ushortT Vt[64 * 72];
    __shared__ __align__(16) ushortT Ps[8 * 16 * 72];

    const int tid = threadIdx.x;
    const int lane = tid & 63;
    const int wv = tid >> 6;
    const int lc = lane & 15;
    const int lg = lane >> 4;
    const int qb = blockIdx.x * 128;
    const int h = blockIdx.y, n = blockIdx.z;
    const int b = n / NIMG, i = n - b * NIMG;
    int jl[4];
    { int c = 0; for (int j = 0; j < NIMG; j++) if (j != i) jl[c++] = j; }

    // ---- Q A-fragments in registers for whole kernel ----
    short8v qfrag[2];
    {
        const ushortT* qrow = Qg + ((size_t)(n * HEADS + h) * T_DIM + (qb + wv * 16 + lc)) * HD;
        #pragma unroll
        for (int dh = 0; dh < 2; dh++)
            qfrag[dh] = *(const short8v*)(qrow + dh * 32 + lg * 8);
    }

    // staging: 512 threads x 16B = 64 rows x 64 d bf16
    const int srow = tid >> 3;
    const int sc8 = (tid & 7) * 8;
    short8v kreg, vreg;

    auto ctxbase = [&](int cr) -> size_t {
        int j, st;
        if (cr < 4 * NSEL) { j = jl[cr >> 9]; st = idxg[j * NSEL + (cr & (NSEL - 1))]; }
        else               { j = i;           st = cr - 4 * NSEL; }
        return (((size_t)(b * NIMG + j) * HEADS + h) * T_DIM + st) * (size_t)HD;
    };
    auto gatherK = [&](int t) { kreg = *(const short8v*)(Kg + ctxbase(t * KT + srow) + sc8); };
    auto gatherV = [&](int t) { vreg = *(const short8v*)(Vg + ctxbase(t * KT + srow) + sc8); };
    auto writeK = [&]() { *(short8v*)&Ks[srow * 72 + sc8] = kreg; };
    auto writeVt = [&]() {
        const int xk = (tid & 7) << 3;
        #pragma unroll
        for (int e = 0; e < 8; e++)
            Vt[(sc8 + e) * 72 + (srow ^ xk)] = (ushortT)vreg[e];
    };

    float4v o[4];
    float mrow[4], lrow[4];
    #pragma unroll
    for (int d16 = 0; d16 < 4; d16++) o[d16] = (float4v){0.f, 0.f, 0.f, 0.f};
    #pragma unroll
    for (int r = 0; r < 4; r++) { mrow[r] = -INFINITY; lrow[r] = 0.f; }

    const int pw = wv * 16 * 72;

    gatherK(0); gatherV(0);

    for (int t = 0; t < NT; t++) {
        writeK(); writeVt();
        __syncthreads();                      // B1: K/V(t) visible
        if (t + 1 < NT) gatherK(t + 1);

        // ---- S = Q K^T ----
        float4v s[4];
        #pragma unroll
        for (int k16 = 0; k16 < 4; k16++) {
            float4v z = {0.f, 0.f, 0.f, 0.f};
            #pragma unroll
            for (int dh = 0; dh < 2; dh++) {
                short8v bf = *(const short8v*)&Ks[(k16 * 16 + lc) * 72 + dh * 32 + lg * 8];
                z = __builtin_amdgcn_mfma_f32_16x16x32_bf16(qfrag[dh], bf, z, 0, 0, 0);
            }
            s[k16] = z;
        }

        // ---- online softmax ----
        float corr[4];
        #pragma unroll
        for (int r = 0; r < 4; r++) {
            float lm = fmaxf(fmaxf(s[0][r], s[1][r]), fmaxf(s[2][r], s[3][r]));
            lm = fmaxf(lm, __shfl_xor(lm, 1));
            lm = fmaxf(lm, __shfl_xor(lm, 2));
            lm = fmaxf(lm, __shfl_xor(lm, 4));
            lm = fmaxf(lm, __shfl_xor(lm, 8));
            float mn = fmaxf(mrow[r], lm);
            corr[r] = __expf(mrow[r] - mn);
            mrow[r] = mn;
            float p0 = __expf(s[0][r] - mn);
            float p1 = __expf(s[1][r] - mn);
            float p2 = __expf(s[2][r] - mn);
            float p3 = __expf(s[3][r] - mn);
            s[0][r] = p0; s[1][r] = p1; s[2][r] = p2; s[3][r] = p3;
            float rs = p0 + p1 + p2 + p3;
            rs += __shfl_xor(rs, 1);
            rs += __shfl_xor(rs, 2);
            rs += __shfl_xor(rs, 4);
            rs += __shfl_xor(rs, 8);
            lrow[r] = lrow[r] * corr[r] + rs;
        }

        // ---- P -> bf16 per-wave LDS ----
        #pragma unroll
        for (int k16 = 0; k16 < 4; k16++)
            #pragma unroll
            for (int r = 0; r < 4; r++)
                Ps[pw + (lg * 4 + r) * 72 + k16 * 16 + lc] = f2bf(s[k16][r]);
        asm volatile("s_waitcnt lgkmcnt(0)" ::: "memory");
        __builtin_amdgcn_sched_barrier(0);

        if (t + 1 < NT) gatherV(t + 1);

        #pragma unroll
        for (int d16 = 0; d16 < 4; d16++)
            #pragma unroll
            for (int r = 0; r < 4; r++) o[d16][r] *= corr[r];

        // ---- O += P V ----
        #pragma unroll
        for (int kch = 0; kch < 2; kch++) {
            short8v pa = *(const short8v*)&Ps[pw + lc * 72 + kch * 32 + lg * 8];
            #pragma unroll
            for (int d16 = 0; d16 < 4; d16++) {
                int d = d16 * 16 + lc;
                int xk = ((d >> 3) & 7) << 3;
                short8v vb = *(const short8v*)&Vt[d * 72 + ((kch * 32 + lg * 8) ^ xk)];
                o[d16] = __builtin_amdgcn_mfma_f32_16x16x32_bf16(pa, vb, o[d16], 0, 0, 0);
            }
        }

        __syncthreads();                      // B2: reads of K/V(t) done
    }

    // ---- epilogue: O bf16 row-major [M][C] ----
    #pragma unroll
    for (int r = 0; r < 4; r++) {
        float inv = 1.0f / lrow[r];
        size_t row = (size_t)(n * T_DIM + qb + wv * 16 + lg * 4 + r) * C_DIM + h * HD;
        #pragma unroll
        for (int d16 = 0; d16 < 4; d16++)
            Og[row + d16 * 16 + lc] = f2bf(o[d16][r] * inv);
    }
}

extern "C" void kernel_launch(void* const* d_in, const int* in_sizes, int n_in,
                              void* d_out, int out_size, void* d_ws, size_t ws_size,
                              hipStream_t stream) {
    const float* X  = (const float*)d_in[0];
    const int* idx  = (const int*)d_in[1];
    const float* Wq = (const float*)d_in[2];
    const float* Wk = (const float*)d_in[3];
    const float* Wv = (const float*)d_in[4];
    const float* Wo = (const float*)d_in[5];
    const float* bo = (const float*)d_in[6];
    // d_in[7] = heads (20), hard-coded

    const size_t SZ = (size_t)MROWS * C_DIM;       // 13,107,200
    const size_t WZ = (size_t)C_DIM * C_DIM;       // 1,638,400
    ushortT* Xbf = (ushortT*)d_ws;
    ushortT* Wbf = Xbf + SZ;
    ushortT* Qbf = Wbf + 4 * WZ;
    ushortT* Kbf = Qbf + SZ;
    ushortT* Vbf = Kbf + SZ;
    ushortT* Obf = Vbf + SZ;
    // total: (6*SZ + 4*WZ) * 2B = 144.2 MB

    cvt_x<<<dim3(SZ / 1024), 256, 0, stream>>>(X, Xbf);
    cvt_w<<<dim3(40, 40, 4), 256, 0, stream>>>(Wq, Wk, Wv, Wo, Wbf);

    dim3 g1(30, 80);
    mfma_gemm<0><<<g1, 256, 0, stream>>>(Xbf, Wbf, Qbf, Kbf, Vbf,
                                         nullptr, nullptr, nullptr);
    dim3 g2(T_DIM / 128, HEADS, 10);
    attn_mfma<<<g2, 512, 0, stream>>>(Qbf, Kbf, Vbf, idx, Obf);
    dim3 g3(10, 80);
    mfma_gemm<1><<<g3, 256, 0, stream>>>(Obf, Wbf + 3 * WZ, nullptr, nullptr, nullptr,
                                         bo, X, (float*)d_out);
}

// Round 6
// 645.643 us; speedup vs baseline: 8.1836x; 1.3327x over previous
//
#include <hip/hip_runtime.h>
#include <math.h>

#define C_DIM 1280
#define T_DIM 1024
#define NIMG 5
#define HEADS 20
#define HD 64
#define NSEL 512
#define MROWS (10 * T_DIM)      // 10240
#define SCTX (4 * NSEL + T_DIM) // 3072
#define KT 64
#define NT (SCTX / KT)          // 48

typedef unsigned short ushortT;
typedef __attribute__((ext_vector_type(8))) short short8v;
typedef __attribute__((ext_vector_type(4))) short short4v;
typedef __attribute__((ext_vector_type(4))) float float4v;
typedef __attribute__((ext_vector_type(16))) float f32x16;
typedef __attribute__((ext_vector_type(4))) unsigned int uint4v;

// f32 -> bf16 round-to-nearest-even, bit pattern as ushort
static __device__ __forceinline__ ushortT f2bf(float f) {
    union { float f; unsigned u; } v; v.f = f;
    unsigned r = (v.u + 0x7FFFu + ((v.u >> 16) & 1u)) >> 16;
    return (ushortT)r;
}
// packed pair: lo=bf16(a), hi=bf16(b)
static __device__ __forceinline__ unsigned cvtpk(float a, float b) {
    unsigned r;
    asm("v_cvt_pk_bf16_f32 %0, %1, %2" : "=v"(r) : "v"(a), "v"(b));
    return r;
}

// ---------------------------------------------------------------------------
// Prep 1: X f32 -> bf16 row-major [M][K]
// ---------------------------------------------------------------------------
__global__ __launch_bounds__(256) void cvt_x(const float* __restrict__ X,
                                             ushortT* __restrict__ Xbf)
{
    int i = (blockIdx.x * 256 + threadIdx.x) * 4;
    float4 v = *(const float4*)(X + i);
    short4v o = { (short)f2bf(v.x), (short)f2bf(v.y), (short)f2bf(v.z), (short)f2bf(v.w) };
    *(short4v*)(Xbf + i) = o;
}

// ---------------------------------------------------------------------------
// Prep 2: W[z] (k x n f32) -> Wbf[z] (n x k bf16), z in {q,k,v,o}
// ---------------------------------------------------------------------------
__global__ __launch_bounds__(256) void cvt_w(
    const float* __restrict__ Wq, const float* __restrict__ Wk,
    const float* __restrict__ Wv, const float* __restrict__ Wo,
    ushortT* __restrict__ Wbf)
{
    __shared__ float t[32][33];
    const int z = blockIdx.z;
    const float* __restrict__ W = (z == 0) ? Wq : (z == 1) ? Wk : (z == 2) ? Wv : Wo;
    const int nt = blockIdx.x * 32, kt = blockIdx.y * 32;
    const int x = threadIdx.x & 31, y = threadIdx.x >> 5;
    #pragma unroll
    for (int r = 0; r < 4; r++)
        t[y + r * 8][x] = W[(size_t)(kt + y + r * 8) * C_DIM + nt + x];
    __syncthreads();
    ushortT* __restrict__ Wz = Wbf + (size_t)z * C_DIM * C_DIM;
    #pragma unroll
    for (int r = 0; r < 4; r++)
        Wz[(size_t)(nt + y + r * 8) * C_DIM + kt + x] = f2bf(t[x][y + r * 8]);
}

// ---------------------------------------------------------------------------
// MFMA GEMM (unchanged from round 5): C(128x128) = A[M][K]bf16 x W^T[n][k]bf16.
// MODE 0: qkv scatter to [n][h][t][d] bf16 (Q pre-scaled 1/8).
// MODE 1: out = acc + bias + residual, f32 row-major.
// ---------------------------------------------------------------------------
template<int MODE>
__global__ __launch_bounds__(256) void mfma_gemm(
    const ushortT* __restrict__ Abf, const ushortT* __restrict__ Wbf,
    ushortT* __restrict__ Qo, ushortT* __restrict__ Ko, ushortT* __restrict__ Vo,
    const float* __restrict__ bias, const float* __restrict__ Xres,
    float* __restrict__ Out)
{
    __shared__ __align__(16) ushortT As[128 * 64];
    __shared__ __align__(16) ushortT Bs[128 * 64];
    const int tid = threadIdx.x;
    const int lane = tid & 63, wv = tid >> 6;
    const int lc = lane & 15, lg = lane >> 4;
    const int wr = wv >> 1, wc = wv & 1;
    int wsel, cb;
    if (MODE == 0) { wsel = blockIdx.x / 10; cb = blockIdx.x % 10; }
    else           { wsel = 0;              cb = blockIdx.x; }
    const int r0 = blockIdx.y * 128, c0 = cb * 128;
    const ushortT* __restrict__ A0 = Abf + (size_t)r0 * C_DIM;
    const ushortT* __restrict__ B0 = Wbf + (size_t)wsel * C_DIM * C_DIM + (size_t)c0 * C_DIM;

    int g_off[4], l_off[4];
    #pragma unroll
    for (int p = 0; p < 4; p++) {
        int idx = p * 256 + tid;
        int row = idx >> 3, cslot = idx & 7;
        int csrc = cslot ^ (row & 7);
        g_off[p] = row * C_DIM + csrc * 8;
        l_off[p] = row * 64 + cslot * 8;
    }
    short8v Ar[4], Br[4];

    float4v acc[4][4];
    #pragma unroll
    for (int mi = 0; mi < 4; mi++)
        #pragma unroll
        for (int ni = 0; ni < 4; ni++) acc[mi][ni] = (float4v){0.f, 0.f, 0.f, 0.f};

    #pragma unroll
    for (int p = 0; p < 4; p++) {
        Ar[p] = *(const short8v*)(A0 + g_off[p]);
        Br[p] = *(const short8v*)(B0 + g_off[p]);
    }

    for (int kk = 0; kk < C_DIM; kk += 64) {
        __syncthreads();
        #pragma unroll
        for (int p = 0; p < 4; p++) {
            *(short8v*)&As[l_off[p]] = Ar[p];
            *(short8v*)&Bs[l_off[p]] = Br[p];
        }
        __syncthreads();
        if (kk + 64 < C_DIM) {
            #pragma unroll
            for (int p = 0; p < 4; p++) {
                Ar[p] = *(const short8v*)(A0 + g_off[p] + kk + 64);
                Br[p] = *(const short8v*)(B0 + g_off[p] + kk + 64);
            }
        }
        #pragma unroll
        for (int dh = 0; dh < 2; dh++) {
            short8v af[4], bf[4];
            const int cslot = ((dh * 4 + lg) ^ (lc & 7)) * 8;
            #pragma unroll
            for (int mi = 0; mi < 4; mi++)
                af[mi] = *(const short8v*)&As[(wr * 64 + mi * 16 + lc) * 64 + cslot];
            #pragma unroll
            for (int ni = 0; ni < 4; ni++)
                bf[ni] = *(const short8v*)&Bs[(wc * 64 + ni * 16 + lc) * 64 + cslot];
            #pragma unroll
            for (int mi = 0; mi < 4; mi++)
                #pragma unroll
                for (int ni = 0; ni < 4; ni++)
                    acc[mi][ni] = __builtin_amdgcn_mfma_f32_16x16x32_bf16(
                        af[mi], bf[ni], acc[mi][ni], 0, 0, 0);
        }
    }

    if (MODE == 0) {
        ushortT* __restrict__ OutW = (wsel == 0) ? Qo : (wsel == 1) ? Ko : Vo;
        const float scale = (wsel == 0) ? 0.125f : 1.0f;
        #pragma unroll
        for (int mi = 0; mi < 4; mi++)
            #pragma unroll
            for (int reg = 0; reg < 4; reg++) {
                int row = r0 + wr * 64 + mi * 16 + lg * 4 + reg;
                int nimg = row >> 10, t = row & 1023;
                #pragma unroll
                for (int ni = 0; ni < 4; ni++) {
                    int col = c0 + wc * 64 + ni * 16 + lc;
                    int hh = col >> 6, d = col & 63;
                    OutW[((size_t)(nimg * HEADS + hh) * T_DIM + t) * HD + d] =
                        f2bf(acc[mi][ni][reg] * scale);
                }
            }
    } else {
        #pragma unroll
        for (int mi = 0; mi < 4; mi++)
            #pragma unroll
            for (int reg = 0; reg < 4; reg++) {
                int row = r0 + wr * 64 + mi * 16 + lg * 4 + reg;
                #pragma unroll
                for (int ni = 0; ni < 4; ni++) {
                    int col = c0 + wc * 64 + ni * 16 + lc;
                    size_t o = (size_t)row * C_DIM + col;
                    Out[o] = acc[mi][ni][reg] + bias[col] + Xres[o];
                }
            }
    }
}

// ---------------------------------------------------------------------------
// Flash attention v3: 32x32x16 MFMA, swapped operands, P in registers.
// 256 thr = 4 waves x 32 q-rows. lane = lq + 32*h2 (lq=lane&31, h2=lane>>5).
// S^T = K·Q^T  -> D col = q = lq (softmax fully lane-local).
// O^T = V^T·P^T -> D col = q = lq (rescale/l lane-local).
// P^T B-frags built in-register: 16 cvt_pk + 8 shfl_xor(32) per tile.
// LDS: Ks[64][72] + Vt[64][72] bf16, XOR-swizzled; reused for O staging.
// ---------------------------------------------------------------------------
__global__ __launch_bounds__(256) void attn_mfma32(
    const ushortT* __restrict__ Qg, const ushortT* __restrict__ Kg,
    const ushortT* __restrict__ Vg, const int* __restrict__ idxg,
    ushortT* __restrict__ Og)
{
    __shared__ __align__(16) ushortT lds[128 * 72];   // 18432 B
    ushortT* __restrict__ Ks = lds;            // [64 k][72] row-major, swizzled
    ushortT* __restrict__ Vt = lds + 64 * 72;  // [64 d][72 k] transposed, swizzled

    const int tid = threadIdx.x;
    const int lane = tid & 63;
    const int wv = tid >> 6;        // wave 0..3, owns q-rows [wv*32, +32)
    const int lq = lane & 31;
    const int h2 = lane >> 5;
    const int qb = blockIdx.x * 128;
    const int h = blockIdx.y, n = blockIdx.z;
    const int b = n / NIMG, i = n - b * NIMG;

    // ---- Q B-fragments (registers, whole kernel). Q pre-scaled by 1/8. ----
    short8v qfrag[4];
    {
        const ushortT* qrow = Qg + ((size_t)(n * HEADS + h) * T_DIM + (qb + wv * 32 + lq)) * HD;
        #pragma unroll
        for (int dt = 0; dt < 4; dt++)
            qfrag[dt] = *(const short8v*)(qrow + dt * 16 + h2 * 8);
    }

    // ---- staging: thread -> ctx-local row sr (0..63), d-chunk sc (16 wide) ----
    const int sr = tid >> 2;
    const int sc = (tid & 3) * 16;
    short8v kr0, kr1, vr0, vr1;

    auto ctxbase = [&](int cr) -> size_t {
        int j, st;
        if (cr < 4 * NSEL) {
            int jj = cr >> 9; j = jj + (jj >= i);
            st = idxg[j * NSEL + (cr & (NSEL - 1))];
        } else { j = i; st = cr - 4 * NSEL; }
        return (((size_t)(b * NIMG + j) * HEADS + h) * T_DIM + st) * (size_t)HD;
    };
    auto xswz = [](int row) -> int { return 8 * (((row >> 1) ^ (row >> 4)) & 7); };

    auto gatherK = [&](int t) {
        size_t base = ctxbase(t * KT + sr);
        kr0 = *(const short8v*)(Kg + base + sc);
        kr1 = *(const short8v*)(Kg + base + sc + 8);
    };
    auto gatherV = [&](int t) {
        size_t base = ctxbase(t * KT + sr);
        vr0 = *(const short8v*)(Vg + base + sc);
        vr1 = *(const short8v*)(Vg + base + sc + 8);
    };
    auto writeK = [&]() {
        int xb = xswz(sr);
        *(short8v*)&Ks[sr * 72 + (sc ^ xb)] = kr0;
        *(short8v*)&Ks[sr * 72 + ((sc + 8) ^ xb)] = kr1;
    };
    auto writeVt = [&]() {
        #pragma unroll
        for (int e = 0; e < 8; e++) {
            int d0 = sc + e, d1 = sc + 8 + e;
            Vt[d0 * 72 + (sr ^ xswz(d0))] = (ushortT)vr0[e];
            Vt[d1 * 72 + (sr ^ xswz(d1))] = (ushortT)vr1[e];
        }
    };

    f32x16 o0, o1;
    #pragma unroll
    for (int r = 0; r < 16; r++) { o0[r] = 0.f; o1[r] = 0.f; }
    float mrow = -INFINITY, lrow = 0.f;

    gatherK(0); gatherV(0);

    for (int t = 0; t < NT; t++) {
        writeK(); writeVt();
        __syncthreads();                      // B1: K/V(t) visible
        if (t + 1 < NT) gatherK(t + 1);       // in flight over QK

        // ---- S^T = K · Q^T : acc s0 (k 0..31), s1 (k 32..63) ----
        f32x16 s0, s1;
        #pragma unroll
        for (int r = 0; r < 16; r++) { s0[r] = 0.f; s1[r] = 0.f; }
        #pragma unroll
        for (int dt = 0; dt < 4; dt++) {
            const int off = dt * 16 + h2 * 8;
            short8v a0 = *(const short8v*)&Ks[lq * 72 + (off ^ xswz(lq))];
            short8v a1 = *(const short8v*)&Ks[(32 + lq) * 72 + (off ^ xswz(32 + lq))];
            s0 = __builtin_amdgcn_mfma_f32_32x32x16_bf16(a0, qfrag[dt], s0, 0, 0, 0);
            s1 = __builtin_amdgcn_mfma_f32_32x32x16_bf16(a1, qfrag[dt], s1, 0, 0, 0);
        }

        // ---- online softmax: q = lq is lane-local; halves differ only in k ----
        float lm = s0[0];
        #pragma unroll
        for (int r = 1; r < 16; r++) lm = fmaxf(lm, s0[r]);
        #pragma unroll
        for (int r = 0; r < 16; r++) lm = fmaxf(lm, s1[r]);
        lm = fmaxf(lm, __shfl_xor(lm, 32));
        float mn = fmaxf(mrow, lm);
        float corr = __expf(mrow - mn);
        mrow = mn;
        float rs = 0.f;
        #pragma unroll
        for (int r = 0; r < 16; r++) { s0[r] = __expf(s0[r] - mn); rs += s0[r]; }
        #pragma unroll
        for (int r = 0; r < 16; r++) { s1[r] = __expf(s1[r] - mn); rs += s1[r]; }
        rs += __shfl_xor(rs, 32);
        lrow = lrow * corr + rs;

        // ---- pack P to bf16 pairs ----
        unsigned pk0[8], pk1[8];
        #pragma unroll
        for (int m = 0; m < 8; m++) {
            pk0[m] = cvtpk(s0[2 * m], s0[2 * m + 1]);
            pk1[m] = cvtpk(s1[2 * m], s1[2 * m + 1]);
        }
        // ---- exchange across lane-halves: partner needs regs selected by ITS h2
        unsigned rv0[4], rv1[4];
        #pragma unroll
        for (int u = 0; u < 4; u++) {
            const int base = (u & 1) + 4 * (u >> 1);   // 0,1,4,5
            unsigned snd0 = h2 ? pk0[base] : pk0[base + 2];
            unsigned snd1 = h2 ? pk1[base] : pk1[base + 2];
            rv0[u] = (unsigned)__shfl_xor((int)snd0, 32);
            rv1[u] = (unsigned)__shfl_xor((int)snd1, 32);
        }

        if (t + 1 < NT) gatherV(t + 1);       // in flight over PV

        // ---- rescale O ----
        #pragma unroll
        for (int r = 0; r < 16; r++) { o0[r] *= corr; o1[r] *= corr; }

        // ---- O^T += V^T · P^T ----
        #pragma unroll
        for (int kt2 = 0; kt2 < 2; kt2++) {
            #pragma unroll
            for (int kt1 = 0; kt1 < 2; kt1++) {
                const int kt = kt2 * 2 + kt1;
                unsigned a_ = kt2 ? pk1[4 * kt1 + 0] : pk0[4 * kt1 + 0];
                unsigned b_ = kt2 ? pk1[4 * kt1 + 1] : pk0[4 * kt1 + 1];
                unsigned c_ = kt2 ? pk1[4 * kt1 + 2] : pk0[4 * kt1 + 2];
                unsigned d_ = kt2 ? pk1[4 * kt1 + 3] : pk0[4 * kt1 + 3];
                unsigned own0 = h2 ? c_ : a_;
                unsigned own1 = h2 ? d_ : b_;
                unsigned r0_ = kt2 ? rv1[2 * kt1] : rv0[2 * kt1];
                unsigned r1_ = kt2 ? rv1[2 * kt1 + 1] : rv0[2 * kt1 + 1];
                union { uint4v u; short8v s; } pw;
                pw.u = (uint4v){ h2 ? r0_ : own0, h2 ? r1_ : own1,
                                 h2 ? own0 : r0_, h2 ? own1 : r1_ };
                const int off = kt * 16 + h2 * 8;
                short8v va0 = *(const short8v*)&Vt[lq * 72 + (off ^ xswz(lq))];
                short8v va1 = *(const short8v*)&Vt[(32 + lq) * 72 + (off ^ xswz(32 + lq))];
                o0 = __builtin_amdgcn_mfma_f32_32x32x16_bf16(va0, pw.s, o0, 0, 0, 0);
                o1 = __builtin_amdgcn_mfma_f32_32x32x16_bf16(va1, pw.s, o1, 0, 0, 0);
            }
        }

        __syncthreads();                      // B2: reads of K/V(t) done
    }

    // ---- epilogue: O^T regs -> LDS (coalesce) -> global bf16 [M][C] ----
    // element d of row q stored at lds[q*72 + (d ^ xo(q))], xo = 8*(lq>>3)
    {
        float inv = 1.0f / lrow;
        const int orow = wv * 32 + lq;
        const int xo = 8 * (lq >> 3);
        #pragma unroll
        for (int g = 0; g < 4; g++) {
            unsigned w0 = cvtpk(o0[4 * g] * inv, o0[4 * g + 1] * inv);
            unsigned w1 = cvtpk(o0[4 * g + 2] * inv, o0[4 * g + 3] * inv);
            int db0 = (8 * g + 4 * h2) ^ xo;
            *(unsigned*)&lds[orow * 72 + db0] = w0;
            *(unsigned*)&lds[orow * 72 + db0 + 2] = w1;
            unsigned w2 = cvtpk(o1[4 * g] * inv, o1[4 * g + 1] * inv);
            unsigned w3 = cvtpk(o1[4 * g + 2] * inv, o1[4 * g + 3] * inv);
            int db1 = (32 + 8 * g + 4 * h2) ^ xo;
            *(unsigned*)&lds[orow * 72 + db1] = w2;
            *(unsigned*)&lds[orow * 72 + db1 + 2] = w3;
        }
    }
    __syncthreads();
    {
        const int q = tid >> 1;
        const int dh = (tid & 1) * 32;
        const int xq = 8 * ((q & 31) >> 3);
        size_t gbase = (size_t)(n * T_DIM + qb + q) * C_DIM + h * HD + dh;
        #pragma unroll
        for (int jj = 0; jj < 4; jj++) {
            short8v v = *(const short8v*)&lds[q * 72 + ((dh + 8 * jj) ^ xq)];
            *(short8v*)(Og + gbase + 8 * jj) = v;
        }
    }
}

extern "C" void kernel_launch(void* const* d_in, const int* in_sizes, int n_in,
                              void* d_out, int out_size, void* d_ws, size_t ws_size,
                              hipStream_t stream) {
    const float* X  = (const float*)d_in[0];
    const int* idx  = (const int*)d_in[1];
    const float* Wq = (const float*)d_in[2];
    const float* Wk = (const float*)d_in[3];
    const float* Wv = (const float*)d_in[4];
    const float* Wo = (const float*)d_in[5];
    const float* bo = (const float*)d_in[6];
    // d_in[7] = heads (20), hard-coded

    const size_t SZ = (size_t)MROWS * C_DIM;       // 13,107,200
    const size_t WZ = (size_t)C_DIM * C_DIM;       // 1,638,400
    ushortT* Xbf = (ushortT*)d_ws;
    ushortT* Wbf = Xbf + SZ;
    ushortT* Qbf = Wbf + 4 * WZ;
    ushortT* Kbf = Qbf + SZ;
    ushortT* Vbf = Kbf + SZ;
    ushortT* Obf = Vbf + SZ;
    // total: (6*SZ + 4*WZ) * 2B = 144.2 MB

    cvt_x<<<dim3(SZ / 1024), 256, 0, stream>>>(X, Xbf);
    cvt_w<<<dim3(40, 40, 4), 256, 0, stream>>>(Wq, Wk, Wv, Wo, Wbf);

    dim3 g1(30, 80);
    mfma_gemm<0><<<g1, 256, 0, stream>>>(Xbf, Wbf, Qbf, Kbf, Vbf,
                                         nullptr, nullptr, nullptr);
    dim3 g2(T_DIM / 128, HEADS, 10);
    attn_mfma32<<<g2, 256, 0, stream>>>(Qbf, Kbf, Vbf, idx, Obf);
    dim3 g3(10, 80);
    mfma_gemm<1><<<g3, 256, 0, stream>>>(Obf, Wbf + 3 * WZ, nullptr, nullptr, nullptr,
                                         bo, X, (float*)d_out);
}